// Round 1
// baseline (66.000 us; speedup 1.0000x reference)
//
#include <hip/hip_runtime.h>

// dw = LR * (post^T @ pre / B - WD * W)
// pre:  (B=128, PRE=1024)  f32
// post: (B=128, POST=1024) f32
// W:    (POST, PRE)        f32
// out:  (POST, PRE)        f32

constexpr int   KB    = 128;   // batch (reduction dim)
constexpr int   MPOST = 1024;  // output rows
constexpr int   NPRE  = 1024;  // output cols
constexpr int   LSTR  = 68;    // LDS row stride (64 + 4 pad, keeps 16B alignment)
constexpr float LR    = 0.005f;
constexpr float WD    = 0.0001f;

__global__ __launch_bounds__(256) void hebb_kernel(
    const float* __restrict__ pre,
    const float* __restrict__ post,
    const float* __restrict__ W,
    float* __restrict__ out)
{
    // [k][m] layout, k = batch index. 128 rows x 68 floats x 2 tiles = 69632 B LDS.
    __shared__ float As[KB * LSTR];  // post tile: As[k][m]
    __shared__ float Bs[KB * LSTR];  // pre  tile: Bs[k][n]

    const int tx  = threadIdx.x;         // 0..15
    const int ty  = threadIdx.y;         // 0..15
    const int tid = ty * 16 + tx;        // 0..255
    const int bm  = blockIdx.y * 64;     // post (row) tile base
    const int bn  = blockIdx.x * 64;     // pre  (col) tile base

    // --- stage both 128x64 tiles (2048 float4 each; 8 per thread, coalesced) ---
    #pragma unroll
    for (int i = 0; i < 8; ++i) {
        const int idx = i * 256 + tid;       // 0..2047
        const int row = idx >> 4;            // k index
        const int c4  = (idx & 15) * 4;      // column within tile
        const float4 a = *reinterpret_cast<const float4*>(post + row * MPOST + bm + c4);
        const float4 b = *reinterpret_cast<const float4*>(pre  + row * NPRE  + bn + c4);
        *reinterpret_cast<float4*>(&As[row * LSTR + c4]) = a;
        *reinterpret_cast<float4*>(&Bs[row * LSTR + c4]) = b;
    }

    // --- prefetch W micro-tile into registers; the 4 MB W fetch overlaps the k-loop ---
    const int ty4 = ty * 4, tx4 = tx * 4;
    float4 wreg[4];
    #pragma unroll
    for (int i = 0; i < 4; ++i)
        wreg[i] = *reinterpret_cast<const float4*>(W + (size_t)(bm + ty4 + i) * NPRE + bn + tx4);

    __syncthreads();

    // --- K loop: 2 ds_read_b128 + 16 FMA per k ---
    float acc[4][4] = {};
    #pragma unroll 8
    for (int k = 0; k < KB; ++k) {
        const float4 a = *reinterpret_cast<const float4*>(&As[k * LSTR + ty4]);
        const float4 b = *reinterpret_cast<const float4*>(&Bs[k * LSTR + tx4]);
        const float av[4] = {a.x, a.y, a.z, a.w};
        const float bv[4] = {b.x, b.y, b.z, b.w};
        #pragma unroll
        for (int i = 0; i < 4; ++i)
            #pragma unroll
            for (int j = 0; j < 4; ++j)
                acc[i][j] = fmaf(av[i], bv[j], acc[i][j]);
    }

    // --- epilogue: dw = (LR/B)*acc - (LR*WD)*W ---
    const float s1 = LR / (float)KB;
    const float s2 = LR * WD;
    #pragma unroll
    for (int i = 0; i < 4; ++i) {
        float4 o;
        o.x = s1 * acc[i][0] - s2 * wreg[i].x;
        o.y = s1 * acc[i][1] - s2 * wreg[i].y;
        o.z = s1 * acc[i][2] - s2 * wreg[i].z;
        o.w = s1 * acc[i][3] - s2 * wreg[i].w;
        *reinterpret_cast<float4*>(out + (size_t)(bm + ty4 + i) * NPRE + bn + tx4) = o;
    }
}

extern "C" void kernel_launch(void* const* d_in, const int* in_sizes, int n_in,
                              void* d_out, int out_size, void* d_ws, size_t ws_size,
                              hipStream_t stream) {
    const float* pre  = (const float*)d_in[0];  // pre_spikes  (128, 1024)
    const float* post = (const float*)d_in[1];  // post_spikes (128, 1024)
    const float* W    = (const float*)d_in[2];  // weights     (1024, 1024)
    float* out = (float*)d_out;

    dim3 grid(NPRE / 64, MPOST / 64);  // 16 x 16 = 256 blocks (1 per CU)
    dim3 block(16, 16);                // 256 threads = 4 waves
    hebb_kernel<<<grid, block, 0, stream>>>(pre, post, W, out);
}

// Round 4
// 63.055 us; speedup vs baseline: 1.0467x; 1.0467x over previous
//
#include <hip/hip_runtime.h>

// dw = LR * (post^T @ pre / B - WD * W)   via bf16 MFMA (32x32x16)
// pre:  (K=128, NPRE=1024)  f32   [batch-major]
// post: (K=128, MPOST=1024) f32
// W/out: (1024, 1024) f32
//
// 1024 blocks x 64 threads (1 wave). Each wave: one 32x32 output tile.
// Both spike tiles staged fp32->bf16 TRANSPOSED into LDS as [m][k] /
// [n][k] (MFMA wants contiguous-k per lane; memory is k-strided).
// LDS row stride 136 bf16: both ds_write_b128 staging and ds_read_b128
// fragment reads land on 8 distinct bank-quads covering all 32 banks ->
// structural floor, no conflicts.

using f32x16 = __attribute__((ext_vector_type(16))) float;
using short8 = __attribute__((ext_vector_type(8))) short;

constexpr int   N    = 1024;
constexpr int   K    = 128;
constexpr int   LSTR = 136;   // bf16 elems per LDS row (128 + 8 pad)
constexpr float LR   = 0.005f;
constexpr float WD   = 0.0001f;

__device__ inline unsigned short f2bf(float x) {
    union { float f; unsigned int u; } c; c.f = x;
    // round-to-nearest-even
    return (unsigned short)((c.u + 0x7FFFu + ((c.u >> 16) & 1u)) >> 16);
}

__global__ __launch_bounds__(64) void hebb_mfma(
    const float* __restrict__ pre,
    const float* __restrict__ post,
    const float* __restrict__ W,
    float* __restrict__ out)
{
    __shared__ unsigned short A_lds[32 * LSTR];  // A[m][k] = post[k][bm+m]
    __shared__ unsigned short B_lds[32 * LSTR];  // B[n][k] = pre [k][bn+n]

    const int l  = threadIdx.x;        // lane 0..63
    const int bm = blockIdx.y * 32;    // post rows of this tile
    const int bn = blockIdx.x * 32;    // pre  cols of this tile

    // staging task split: 8 m-groups x 8 k-groups (x2 passes for K=128)
    const int m4 = (l & 7) * 4;        // 4 consecutive m per thread
    const int k8 = (l >> 3) * 8;       // 8 consecutive k per thread

    #pragma unroll
    for (int p = 0; p < 2; ++p) {
        const int kb = k8 + p * 64;
        float4 av[8], bv[8];
        #pragma unroll
        for (int j = 0; j < 8; ++j) {
            av[j] = *(const float4*)(post + (size_t)(kb + j) * N + bm + m4);
            bv[j] = *(const float4*)(pre  + (size_t)(kb + j) * N + bn + m4);
        }
        #pragma unroll
        for (int i = 0; i < 4; ++i) {
            short8 pa, pb;
            #pragma unroll
            for (int j = 0; j < 8; ++j) {
                const float* fa = (const float*)&av[j];
                const float* fb = (const float*)&bv[j];
                pa[j] = (short)f2bf(fa[i]);   // A[m4+i][kb+j]
                pb[j] = (short)f2bf(fb[i]);   // B[n4+i][kb+j]
            }
            *(short8*)&A_lds[(m4 + i) * LSTR + kb] = pa;
            *(short8*)&B_lds[(m4 + i) * LSTR + kb] = pb;
        }
    }

    // W prefetch into registers: overlaps the LDS drain + MFMA loop.
    // C/D layout (m74/m101): col = lane&31, row = (reg&3)+8*(reg>>2)+4*(lane>>5)
    const int col   = l & 31;
    const int rbase = 4 * (l >> 5);
    float wv[16];
    #pragma unroll
    for (int r = 0; r < 16; ++r) {
        const int row = (r & 3) + 8 * (r >> 2) + rbase;
        wv[r] = W[(size_t)(bm + row) * N + bn + col];
    }

    __syncthreads();

    // K-loop: 8 x mfma_32x32x16. A-frag: lane l = row l&31, k = 8*(l>>5)+j.
    f32x16 acc = {};
    const int hh = 8 * (l >> 5);
    #pragma unroll
    for (int kk = 0; kk < 8; ++kk) {
        short8 a = *(const short8*)&A_lds[(l & 31) * LSTR + kk * 16 + hh];
        short8 b = *(const short8*)&B_lds[(l & 31) * LSTR + kk * 16 + hh];
        acc = __builtin_amdgcn_mfma_f32_32x32x16_bf16(a, b, acc, 0, 0, 0);
    }

    // epilogue: dw = (LR/B)*acc - (LR*WD)*W ; dword stores, 2x128B segments/instr
    const float s1 = LR / 128.0f;
    const float s2 = LR * WD;
    #pragma unroll
    for (int r = 0; r < 16; ++r) {
        const int row = (r & 3) + 8 * (r >> 2) + rbase;
        out[(size_t)(bm + row) * N + bn + col] = s1 * acc[r] - s2 * wv[r];
    }
}

extern "C" void kernel_launch(void* const* d_in, const int* in_sizes, int n_in,
                              void* d_out, int out_size, void* d_ws, size_t ws_size,
                              hipStream_t stream) {
    const float* pre  = (const float*)d_in[0];  // pre_spikes  (128, 1024)
    const float* post = (const float*)d_in[1];  // post_spikes (128, 1024)
    const float* W    = (const float*)d_in[2];  // weights     (1024, 1024)
    float* out = (float*)d_out;

    dim3 grid(N / 32, N / 32);  // 32 x 32 = 1024 blocks -> 4 blocks/CU
    dim3 block(64);             // 1 wave per block
    hebb_mfma<<<grid, block, 0, stream>>>(pre, post, W, out);
}